// Round 2
// baseline (290.520 us; speedup 1.0000x reference)
//
#include <hip/hip_runtime.h>
#include <math.h>

#define BATCH 128
#define NANCH 8400
#define NMSK  300
#define KPT   17
#define OUTC  56   // 4 box + 1 score + 34 kpt + 17 vis
#define CAND  768  // candidate slots (>=300 + tie margin)
#define NTHR  1024

__device__ __forceinline__ void prior_of(int i, float& stride, float& cx, float& cy) {
    int row, col;
    if (i < 6400)      { stride = 8.0f;  row = i / 80;              col = i - row * 80; }
    else if (i < 8000) { int ii = i - 6400; stride = 16.0f; row = ii / 40; col = ii - row * 40; }
    else               { int ii = i - 8000; stride = 32.0f; row = ii / 20; col = ii - row * 20; }
    cx = ((float)col + 0.5f) * stride;
    cy = ((float)row + 0.5f) * stride;
}

// ---------------------------------------------------------------------------
// K1: all B*N fused scores (np-f32-exact) -> sc bits. Massively parallel.
// DO NOT change this math: bit-exact vs np reference (absmax 0.0 in R2/R3).
// ---------------------------------------------------------------------------
__global__ __launch_bounds__(256) void scores_kernel(
    const float* __restrict__ cls, const float* __restrict__ obj,
    unsigned int* __restrict__ sc)
{
    int i = blockIdx.x * 256 + threadIdx.x;
    if (i < BATCH * NANCH) {
        float ea = (float)exp(-(double)cls[i]);   // correctly-rounded f32 exp == np.exp
        float eo = (float)exp(-(double)obj[i]);
        float sa = 1.0f / (1.0f + ea);
        float so = 1.0f / (1.0f + eo);
        sc[i] = __float_as_uint(sa * so);
    }
}

// ---------------------------------------------------------------------------
// K2: per-batch everything. 128 blocks x 1024 threads.
//   radix-select exact f32 top-300 -> rank order -> box decode -> NMS bitmask
//   -> (wave0: register-replicated greedy scan || waves1-15: kpt/vis writes)
//   -> cols 0..4 write.
// R4/R5 change: wave-aggregated LDS atomics in the radix histogram +
//   compaction. Score bits cluster into ~3 top-byte bins (sigmoid*sigmoid in
//   (0,1)), so the old per-element atomicAdd serialized ~8400 same-address
//   LDS RMWs per block. Leader/ballot aggregation issues one atomic per wave
//   per DISTINCT bin (~64x fewer serialized ops in round 3). Plus uint4
//   staging of score bits (8400 = 2100*4, 16B-aligned per batch).
// ---------------------------------------------------------------------------
__global__ __launch_bounds__(NTHR) void fused_kernel(
    const float* __restrict__ cls, const float* __restrict__ obj,
    const unsigned int* __restrict__ sc_g, int has_sc,
    const float* __restrict__ bbox, const float* __restrict__ kofs,
    const float* __restrict__ kvis, float* __restrict__ out)
{
    const int b = blockIdx.x;
    const int tid = threadIdx.x;
    const int lane = tid & 63;

    __shared__ __align__(16) unsigned int sc[NANCH];
    __shared__ unsigned int hist[256];
    __shared__ unsigned int suf[256];
    __shared__ unsigned int sh_prefix, sh_k, sh_cnt;
    __shared__ unsigned long long ckey[CAND];   // packed (bits<<32)|(~idx)
    __shared__ float bx1[NMSK], by1[NMSK], bx2[NMSK], by2[NMSK], area[NMSK];
    __shared__ float sval[NMSK], pst[NMSK], ppx[NMSK], ppy[NMSK];
    __shared__ int   sidx[NMSK];
    __shared__ unsigned long long supl[NMSK * 6];  // stride 6 for 16B alignment
    __shared__ unsigned long long keepw[5];

    // ---- stage score bits (uint4: 8400 = 2100*4, 33600B/batch is 16B-aligned) ----
    if (has_sc) {
        const uint4* s4 = (const uint4*)(sc_g + (size_t)b * NANCH);
        uint4* d4 = (uint4*)sc;
        for (int i = tid; i < NANCH / 4; i += NTHR) d4[i] = s4[i];
    } else {
        const float* c = cls + (size_t)b * NANCH;
        const float* o = obj + (size_t)b * NANCH;
        for (int i = tid; i < NANCH; i += NTHR) {
            float ea = (float)exp(-(double)c[i]);
            float eo = (float)exp(-(double)o[i]);
            sc[i] = __float_as_uint((1.0f / (1.0f + ea)) * (1.0f / (1.0f + eo)));
        }
    }
    if (tid == 0) { sh_prefix = 0u; sh_k = NMSK; sh_cnt = 0u; }
    __syncthreads();

    // ---- radix-select exact 300th-largest f32 bit pattern ----
    for (int r = 3; r >= 0; --r) {
        if (tid < 256) hist[tid] = 0u;
        __syncthreads();
        unsigned int pfx  = sh_prefix;
        unsigned int kcur = sh_k;
        // uniform trip count so __ballot stays wave-convergent
        for (int base = 0; base < NANCH; base += NTHR) {
            int i = base + tid;
            bool valid = (i < NANCH);
            unsigned int key = valid ? sc[i] : 0u;
            bool match = valid && ((r == 3) || ((key >> ((r + 1) * 8)) == pfx));
            unsigned int bin = (key >> (r * 8)) & 0xFFu;
            // wave-aggregated atomic: one add per distinct bin per wave
            unsigned long long todo = __ballot(match);
            while (todo) {
                int leader = (int)__ffsll((long long)todo) - 1;
                unsigned int lb = (unsigned int)__shfl((int)bin, leader, 64);
                unsigned long long peers = __ballot(match && (bin == lb)) & todo;
                if (lane == leader)
                    atomicAdd(&hist[lb], (unsigned int)__popcll(peers));
                todo &= ~peers;
            }
        }
        __syncthreads();
        // wave 0: butterfly suffix-scan of 256 bins (4 bins/lane)
        if (tid < 64) {
            int l = tid;
            unsigned int b0 = hist[4 * l + 0], b1 = hist[4 * l + 1];
            unsigned int b2 = hist[4 * l + 2], b3 = hist[4 * l + 3];
            unsigned int tot = b0 + b1 + b2 + b3;
            unsigned int v = tot;
            #pragma unroll
            for (int d = 1; d < 64; d <<= 1) {
                unsigned int t2 = (unsigned int)__shfl_down((int)v, d, 64);
                if (l + d < 64) v += t2;
            }
            unsigned int above = v - tot;        // sum over lanes > l
            suf[4 * l + 3] = above + b3;
            suf[4 * l + 2] = above + b3 + b2;
            suf[4 * l + 1] = above + b3 + b2 + b1;
            suf[4 * l + 0] = above + tot;
        }
        __syncthreads();
        if (tid < 256) {
            unsigned int ge     = suf[tid];
            unsigned int genext = (tid < 255) ? suf[tid + 1] : 0u;
            if (ge >= kcur && genext < kcur) {   // exactly one thread
                sh_prefix = (pfx << 8) | (unsigned int)tid;
                sh_k      = kcur - genext;
            }
        }
        __syncthreads();
    }

    // ---- compact all keys >= pivot (wave-aggregated counter) ----
    unsigned int pivot_bits = sh_prefix;
    for (int base = 0; base < NANCH; base += NTHR) {
        int i = base + tid;
        bool valid = (i < NANCH);
        unsigned int key = valid ? sc[i] : 0u;
        bool pred = valid && (key >= pivot_bits);
        unsigned long long m = __ballot(pred);
        unsigned int cnt = (unsigned int)__popcll(m);
        unsigned int wbase = 0u;
        if (lane == 0 && cnt) wbase = atomicAdd(&sh_cnt, cnt);
        wbase = (unsigned int)__shfl((int)wbase, 0, 64);
        if (pred) {
            unsigned int p = wbase + (unsigned int)__popcll(m & ((1ull << lane) - 1ull));
            if (p < CAND)
                ckey[p] = ((unsigned long long)key << 32)
                        | (unsigned long long)(0xFFFFFFFFu - (unsigned int)i);
        }
    }
    __syncthreads();
    unsigned int M = sh_cnt; if (M > CAND) M = CAND;

    // ---- rank order (score desc, idx asc == lax.top_k); write into LDS ----
    if (tid < (int)M) {
        unsigned long long mine = ckey[tid];
        int rank = 0;
        for (unsigned int t2 = 0; t2 < M; ++t2) rank += (ckey[t2] > mine) ? 1 : 0;
        if (rank < NMSK) {
            sidx[rank] = (int)(0xFFFFFFFFu - (unsigned int)(mine & 0xFFFFFFFFull));
            sval[rank] = __uint_as_float((unsigned int)(mine >> 32));
        }
    }
    __syncthreads();

    // ---- decode the 300 boxes + priors ----
    if (tid < NMSK) {
        int j = tid;
        int i = sidx[j];
        float stride, cx, cy;
        prior_of(i, stride, cx, cy);
        pst[j] = stride; ppx[j] = cx; ppy[j] = cy;
        float4 bb = *(const float4*)(bbox + ((size_t)b * NANCH + (size_t)i) * 4);
        float x = bb.x * stride + cx;
        float y = bb.y * stride + cy;
        float w = expf(bb.z) * stride;
        float h = expf(bb.w) * stride;
        float x1 = x - 0.5f * w, y1 = y - 0.5f * h;
        float x2 = x + 0.5f * w, y2 = y + 0.5f * h;
        bx1[j] = x1; by1[j] = y1; bx2[j] = x2; by2[j] = y2;
        area[j] = fmaxf(x2 - x1, 0.0f) * fmaxf(y2 - y1, 0.0f);
    }
    __syncthreads();

    // ---- suppression bitmask, task = (row i, word w), <=64 inner iters ----
    for (int t = tid; t < NMSK * 5; t += NTHR) {
        int w = t / NMSK;
        int i = t - w * NMSK;
        int jlo = w * 64; if (jlo < i + 1) jlo = i + 1;
        int jhi = w * 64 + 64; if (jhi > NMSK) jhi = NMSK;
        unsigned long long m = 0;
        float ax1 = bx1[i], ay1 = by1[i], ax2 = bx2[i], ay2 = by2[i], aa = area[i];
        for (int j = jlo; j < jhi; ++j) {
            float lx = fmaxf(ax1, bx1[j]);
            float ly = fmaxf(ay1, by1[j]);
            float rx = fminf(ax2, bx2[j]);
            float ry = fminf(ay2, by2[j]);
            float iw = fmaxf(rx - lx, 0.0f);
            float ih = fmaxf(ry - ly, 0.0f);
            float inter = iw * ih;
            float iou = inter / (aa + area[j] - inter + 1e-7f);
            if (iou > 0.65f) m |= 1ull << (j & 63);
        }
        supl[i * 6 + w] = m;
    }
    __syncthreads();

    // ---- wave0: register-replicated greedy scan || others: kpt/vis writes ----
    if (tid < 64) {
        unsigned long long k0 = ~0ull, k1 = ~0ull, k2 = ~0ull, k3 = ~0ull;
        unsigned long long k4 = (1ull << (NMSK - 256)) - 1ull;
        const unsigned long long* sp = supl;
        #define GSTEP(KW, I) \
            if (((KW) >> ((I) & 63)) & 1ull) { \
                const unsigned long long* s = sp + (size_t)(I) * 6; \
                k0 &= ~s[0]; k1 &= ~s[1]; k2 &= ~s[2]; k3 &= ~s[3]; k4 &= ~s[4]; }
        for (int i = 0;   i < 64;   ++i) { GSTEP(k0, i) }
        for (int i = 64;  i < 128;  ++i) { GSTEP(k1, i) }
        for (int i = 128; i < 192;  ++i) { GSTEP(k2, i) }
        for (int i = 192; i < 256;  ++i) { GSTEP(k3, i) }
        for (int i = 256; i < NMSK; ++i) { GSTEP(k4, i) }
        #undef GSTEP
        if (tid == 0) { keepw[0] = k0; keepw[1] = k1; keepw[2] = k2; keepw[3] = k3; keepw[4] = k4; }
    } else {
        // cols 5..55: gathered kpt decode + vis sigmoid
        const float* kof = kofs + (size_t)b * NANCH * 34;
        const float* kvi = kvis + (size_t)b * NANCH * KPT;
        float* ob = out + (size_t)b * NMSK * OUTC;
        for (int e = tid - 64; e < NMSK * 51; e += NTHR - 64) {
            int j  = e / 51;
            int ci = e - j * 51;
            int i  = sidx[j];
            float v;
            if (ci < 34) {
                float off = kof[(size_t)i * 34 + ci];
                v = off * pst[j] + ((ci & 1) ? ppy[j] : ppx[j]);
            } else {
                float x = kvi[(size_t)i * KPT + (ci - 34)];
                v = 1.0f / (1.0f + expf(-x));
            }
            ob[j * OUTC + 5 + ci] = v;
        }
    }
    __syncthreads();

    // ---- cols 0..4 (box + keep-masked score) ----
    float* ob = out + (size_t)b * NMSK * OUTC;
    for (int t = tid; t < NMSK * 5; t += NTHR) {
        int j  = t / 5;
        int ci = t - j * 5;
        float v;
        if (ci == 0)      v = bx1[j];
        else if (ci == 1) v = by1[j];
        else if (ci == 2) v = bx2[j];
        else if (ci == 3) v = by2[j];
        else {
            bool kp = (keepw[j >> 6] >> (j & 63)) & 1ull;
            v = kp ? sval[j] : 0.0f;
        }
        ob[j * OUTC + ci] = v;
    }
}

// ---------------------------------------------------------------------------
extern "C" void kernel_launch(void* const* d_in, const int* in_sizes, int n_in,
                              void* d_out, int out_size, void* d_ws, size_t ws_size,
                              hipStream_t stream) {
    const float* cls  = (const float*)d_in[0];  // [B,N,1]
    const float* bbox = (const float*)d_in[1];  // [B,N,4]
    const float* obj  = (const float*)d_in[2];  // [B,N]
    const float* kofs = (const float*)d_in[3];  // [B,N,17,2]
    const float* kvis = (const float*)d_in[4];  // [B,N,17]
    float* out = (float*)d_out;                 // [B,300,56]

    size_t need_sc = (size_t)BATCH * NANCH * sizeof(unsigned int);
    unsigned int* sc = (unsigned int*)d_ws;
    int has_sc = (ws_size >= need_sc) ? 1 : 0;

    if (has_sc) {
        int nblk = (BATCH * NANCH + 255) / 256;
        scores_kernel<<<nblk, 256, 0, stream>>>(cls, obj, sc);
    }
    fused_kernel<<<BATCH, NTHR, 0, stream>>>(cls, obj, sc, has_sc,
                                             bbox, kofs, kvis, out);
}

// Round 3
// 286.932 us; speedup vs baseline: 1.0125x; 1.0125x over previous
//
#include <hip/hip_runtime.h>
#include <math.h>

#define BATCH 128
#define NANCH 8400
#define NMSK  300
#define KPT   17
#define OUTC  56   // 4 box + 1 score + 34 kpt + 17 vis
#define CAND  768  // candidate slots (>=300 + tie margin)
#define NTHR  1024

__device__ __forceinline__ void prior_of(int i, float& stride, float& cx, float& cy) {
    int row, col;
    if (i < 6400)      { stride = 8.0f;  row = i / 80;              col = i - row * 80; }
    else if (i < 8000) { int ii = i - 6400; stride = 16.0f; row = ii / 40; col = ii - row * 40; }
    else               { int ii = i - 8000; stride = 32.0f; row = ii / 20; col = ii - row * 20; }
    cx = ((float)col + 0.5f) * stride;
    cy = ((float)row + 0.5f) * stride;
}

// ---------------------------------------------------------------------------
// Single fused kernel. 128 blocks x 1024 threads, one block per batch.
// R6 change: NO WORKSPACE USE. R2 rocprof showed two 585MB fillBufferAligned
// dispatches (88.7+88.2 us) inside the timed region -- the harness re-poisons
// the workspace we touch. fused itself is only 88 us. So scores are computed
// in-block (same bit-exact double-exp math as the old scores_kernel; absmax
// 0.0 verified on this exact formula) and d_ws is never read or written.
//   Phases: score bits -> radix-select exact top-300 -> rank order -> box
//   decode -> NMS bitmask -> (wave0 greedy scan || waves1-15 kpt/vis) ->
//   cols 0..4.
// ---------------------------------------------------------------------------
__global__ __launch_bounds__(NTHR) void fused_kernel(
    const float* __restrict__ cls, const float* __restrict__ obj,
    const float* __restrict__ bbox, const float* __restrict__ kofs,
    const float* __restrict__ kvis, float* __restrict__ out)
{
    const int b = blockIdx.x;
    const int tid = threadIdx.x;
    const int lane = tid & 63;

    __shared__ __align__(16) unsigned int sc[NANCH];
    __shared__ unsigned int hist[256];
    __shared__ unsigned int suf[256];
    __shared__ unsigned int sh_prefix, sh_k, sh_cnt;
    __shared__ unsigned long long ckey[CAND];   // packed (bits<<32)|(~idx)
    __shared__ float bx1[NMSK], by1[NMSK], bx2[NMSK], by2[NMSK], area[NMSK];
    __shared__ float sval[NMSK], pst[NMSK], ppx[NMSK], ppy[NMSK];
    __shared__ int   sidx[NMSK];
    __shared__ unsigned long long supl[NMSK * 6];  // stride 6 for 16B alignment
    __shared__ unsigned long long keepw[5];

    // ---- compute score bits in-block (bit-exact vs np: f64 exp -> f32) ----
    // 8400 = 2100*4; per-batch offset 33600B is 16B-aligned -> float4 loads.
    {
        const float4* c4 = (const float4*)(cls + (size_t)b * NANCH);
        const float4* o4 = (const float4*)(obj + (size_t)b * NANCH);
        for (int i = tid; i < NANCH / 4; i += NTHR) {
            float4 cv = c4[i];
            float4 ov = o4[i];
            float sa0 = 1.0f / (1.0f + (float)exp(-(double)cv.x));
            float sa1 = 1.0f / (1.0f + (float)exp(-(double)cv.y));
            float sa2 = 1.0f / (1.0f + (float)exp(-(double)cv.z));
            float sa3 = 1.0f / (1.0f + (float)exp(-(double)cv.w));
            float so0 = 1.0f / (1.0f + (float)exp(-(double)ov.x));
            float so1 = 1.0f / (1.0f + (float)exp(-(double)ov.y));
            float so2 = 1.0f / (1.0f + (float)exp(-(double)ov.z));
            float so3 = 1.0f / (1.0f + (float)exp(-(double)ov.w));
            sc[4 * i + 0] = __float_as_uint(sa0 * so0);
            sc[4 * i + 1] = __float_as_uint(sa1 * so1);
            sc[4 * i + 2] = __float_as_uint(sa2 * so2);
            sc[4 * i + 3] = __float_as_uint(sa3 * so3);
        }
    }
    if (tid == 0) { sh_prefix = 0u; sh_k = NMSK; sh_cnt = 0u; }
    __syncthreads();

    // ---- radix-select exact 300th-largest f32 bit pattern ----
    for (int r = 3; r >= 0; --r) {
        if (tid < 256) hist[tid] = 0u;
        __syncthreads();
        unsigned int pfx  = sh_prefix;
        unsigned int kcur = sh_k;
        // uniform trip count so __ballot stays wave-convergent
        for (int base = 0; base < NANCH; base += NTHR) {
            int i = base + tid;
            bool valid = (i < NANCH);
            unsigned int key = valid ? sc[i] : 0u;
            bool match = valid && ((r == 3) || ((key >> ((r + 1) * 8)) == pfx));
            unsigned int bin = (key >> (r * 8)) & 0xFFu;
            // wave-aggregated atomic: one add per distinct bin per wave
            unsigned long long todo = __ballot(match);
            while (todo) {
                int leader = (int)__ffsll((long long)todo) - 1;
                unsigned int lb = (unsigned int)__shfl((int)bin, leader, 64);
                unsigned long long peers = __ballot(match && (bin == lb)) & todo;
                if (lane == leader)
                    atomicAdd(&hist[lb], (unsigned int)__popcll(peers));
                todo &= ~peers;
            }
        }
        __syncthreads();
        // wave 0: butterfly suffix-scan of 256 bins (4 bins/lane)
        if (tid < 64) {
            int l = tid;
            unsigned int b0 = hist[4 * l + 0], b1 = hist[4 * l + 1];
            unsigned int b2 = hist[4 * l + 2], b3 = hist[4 * l + 3];
            unsigned int tot = b0 + b1 + b2 + b3;
            unsigned int v = tot;
            #pragma unroll
            for (int d = 1; d < 64; d <<= 1) {
                unsigned int t2 = (unsigned int)__shfl_down((int)v, d, 64);
                if (l + d < 64) v += t2;
            }
            unsigned int above = v - tot;        // sum over lanes > l
            suf[4 * l + 3] = above + b3;
            suf[4 * l + 2] = above + b3 + b2;
            suf[4 * l + 1] = above + b3 + b2 + b1;
            suf[4 * l + 0] = above + tot;
        }
        __syncthreads();
        if (tid < 256) {
            unsigned int ge     = suf[tid];
            unsigned int genext = (tid < 255) ? suf[tid + 1] : 0u;
            if (ge >= kcur && genext < kcur) {   // exactly one thread
                sh_prefix = (pfx << 8) | (unsigned int)tid;
                sh_k      = kcur - genext;
            }
        }
        __syncthreads();
    }

    // ---- compact all keys >= pivot (wave-aggregated counter) ----
    unsigned int pivot_bits = sh_prefix;
    for (int base = 0; base < NANCH; base += NTHR) {
        int i = base + tid;
        bool valid = (i < NANCH);
        unsigned int key = valid ? sc[i] : 0u;
        bool pred = valid && (key >= pivot_bits);
        unsigned long long m = __ballot(pred);
        unsigned int cnt = (unsigned int)__popcll(m);
        unsigned int wbase = 0u;
        if (lane == 0 && cnt) wbase = atomicAdd(&sh_cnt, cnt);
        wbase = (unsigned int)__shfl((int)wbase, 0, 64);
        if (pred) {
            unsigned int p = wbase + (unsigned int)__popcll(m & ((1ull << lane) - 1ull));
            if (p < CAND)
                ckey[p] = ((unsigned long long)key << 32)
                        | (unsigned long long)(0xFFFFFFFFu - (unsigned int)i);
        }
    }
    __syncthreads();
    unsigned int M = sh_cnt; if (M > CAND) M = CAND;

    // ---- rank order (score desc, idx asc == lax.top_k); write into LDS ----
    if (tid < (int)M) {
        unsigned long long mine = ckey[tid];
        int rank = 0;
        for (unsigned int t2 = 0; t2 < M; ++t2) rank += (ckey[t2] > mine) ? 1 : 0;
        if (rank < NMSK) {
            sidx[rank] = (int)(0xFFFFFFFFu - (unsigned int)(mine & 0xFFFFFFFFull));
            sval[rank] = __uint_as_float((unsigned int)(mine >> 32));
        }
    }
    __syncthreads();

    // ---- decode the 300 boxes + priors ----
    if (tid < NMSK) {
        int j = tid;
        int i = sidx[j];
        float stride, cx, cy;
        prior_of(i, stride, cx, cy);
        pst[j] = stride; ppx[j] = cx; ppy[j] = cy;
        float4 bb = *(const float4*)(bbox + ((size_t)b * NANCH + (size_t)i) * 4);
        float x = bb.x * stride + cx;
        float y = bb.y * stride + cy;
        float w = expf(bb.z) * stride;
        float h = expf(bb.w) * stride;
        float x1 = x - 0.5f * w, y1 = y - 0.5f * h;
        float x2 = x + 0.5f * w, y2 = y + 0.5f * h;
        bx1[j] = x1; by1[j] = y1; bx2[j] = x2; by2[j] = y2;
        area[j] = fmaxf(x2 - x1, 0.0f) * fmaxf(y2 - y1, 0.0f);
    }
    __syncthreads();

    // ---- suppression bitmask, task = (row i, word w), <=64 inner iters ----
    for (int t = tid; t < NMSK * 5; t += NTHR) {
        int w = t / NMSK;
        int i = t - w * NMSK;
        int jlo = w * 64; if (jlo < i + 1) jlo = i + 1;
        int jhi = w * 64 + 64; if (jhi > NMSK) jhi = NMSK;
        unsigned long long m = 0;
        float ax1 = bx1[i], ay1 = by1[i], ax2 = bx2[i], ay2 = by2[i], aa = area[i];
        for (int j = jlo; j < jhi; ++j) {
            float lx = fmaxf(ax1, bx1[j]);
            float ly = fmaxf(ay1, by1[j]);
            float rx = fminf(ax2, bx2[j]);
            float ry = fminf(ay2, by2[j]);
            float iw = fmaxf(rx - lx, 0.0f);
            float ih = fmaxf(ry - ly, 0.0f);
            float inter = iw * ih;
            float iou = inter / (aa + area[j] - inter + 1e-7f);
            if (iou > 0.65f) m |= 1ull << (j & 63);
        }
        supl[i * 6 + w] = m;
    }
    __syncthreads();

    // ---- wave0: register-replicated greedy scan || others: kpt/vis writes ----
    if (tid < 64) {
        unsigned long long k0 = ~0ull, k1 = ~0ull, k2 = ~0ull, k3 = ~0ull;
        unsigned long long k4 = (1ull << (NMSK - 256)) - 1ull;
        const unsigned long long* sp = supl;
        #define GSTEP(KW, I) \
            if (((KW) >> ((I) & 63)) & 1ull) { \
                const unsigned long long* s = sp + (size_t)(I) * 6; \
                k0 &= ~s[0]; k1 &= ~s[1]; k2 &= ~s[2]; k3 &= ~s[3]; k4 &= ~s[4]; }
        for (int i = 0;   i < 64;   ++i) { GSTEP(k0, i) }
        for (int i = 64;  i < 128;  ++i) { GSTEP(k1, i) }
        for (int i = 128; i < 192;  ++i) { GSTEP(k2, i) }
        for (int i = 192; i < 256;  ++i) { GSTEP(k3, i) }
        for (int i = 256; i < NMSK; ++i) { GSTEP(k4, i) }
        #undef GSTEP
        if (tid == 0) { keepw[0] = k0; keepw[1] = k1; keepw[2] = k2; keepw[3] = k3; keepw[4] = k4; }
    } else {
        // cols 5..55: gathered kpt decode + vis sigmoid
        const float* kof = kofs + (size_t)b * NANCH * 34;
        const float* kvi = kvis + (size_t)b * NANCH * KPT;
        float* ob = out + (size_t)b * NMSK * OUTC;
        for (int e = tid - 64; e < NMSK * 51; e += NTHR - 64) {
            int j  = e / 51;
            int ci = e - j * 51;
            int i  = sidx[j];
            float v;
            if (ci < 34) {
                float off = kof[(size_t)i * 34 + ci];
                v = off * pst[j] + ((ci & 1) ? ppy[j] : ppx[j]);
            } else {
                float x = kvi[(size_t)i * KPT + (ci - 34)];
                v = 1.0f / (1.0f + expf(-x));
            }
            ob[j * OUTC + 5 + ci] = v;
        }
    }
    __syncthreads();

    // ---- cols 0..4 (box + keep-masked score) ----
    float* ob = out + (size_t)b * NMSK * OUTC;
    for (int t = tid; t < NMSK * 5; t += NTHR) {
        int j  = t / 5;
        int ci = t - j * 5;
        float v;
        if (ci == 0)      v = bx1[j];
        else if (ci == 1) v = by1[j];
        else if (ci == 2) v = bx2[j];
        else if (ci == 3) v = by2[j];
        else {
            bool kp = (keepw[j >> 6] >> (j & 63)) & 1ull;
            v = kp ? sval[j] : 0.0f;
        }
        ob[j * OUTC + ci] = v;
    }
}

// ---------------------------------------------------------------------------
extern "C" void kernel_launch(void* const* d_in, const int* in_sizes, int n_in,
                              void* d_out, int out_size, void* d_ws, size_t ws_size,
                              hipStream_t stream) {
    const float* cls  = (const float*)d_in[0];  // [B,N,1]
    const float* bbox = (const float*)d_in[1];  // [B,N,4]
    const float* obj  = (const float*)d_in[2];  // [B,N]
    const float* kofs = (const float*)d_in[3];  // [B,N,17,2]
    const float* kvis = (const float*)d_in[4];  // [B,N,17]
    float* out = (float*)d_out;                 // [B,300,56]

    // d_ws deliberately UNUSED: R2 rocprof showed 2x 585MB poison fills
    // (~177us) in the timed region when the workspace is touched.
    (void)d_ws; (void)ws_size;

    fused_kernel<<<BATCH, NTHR, 0, stream>>>(cls, obj, bbox, kofs, kvis, out);
}